// Round 8
// baseline (159.182 us; speedup 1.0000x reference)
//
#include <hip/hip_runtime.h>

// CIN fused 3-layer, bf16 MFMA (R14): R13 + transient-register surgery.
// cur[sl,n] = sum_f x_f[sl] * S_f[sl,n],  S_f = sum_g h_g[sl] * W[f*64+g, n].
//
// R13 post-mortem: still pinned at 64 VGPR with ~10 regs of residual spill
// (WRITE_SIZE 21 MB). Peak demand inside F_ITER was ~72: a(16) + cur(16) +
// B0-2(12) + xr0-3(16) + sv(4) + addr(8). Empirical law (R9-R13): these
// 1024-thread kernels get EXACTLY 64 VGPRs regardless of declarations --
// demand must fit 64.
//
// R14 (only change = transient shaping, single variable):
//  - B-frag loaded ONE per sub-iter (Bk live = 4 regs, was 12). LDS latency
//    covered by previous sub-iter's fmaf tail + 4 waves/SIMD TLP.
//  - xr loads split 2+2 within the sub-iter (<= 8 xr regs live, was 16).
//  Peak ~56 <= 64 -> zero spill.
//
// Structure (as R13):
//  - 256 blocks x 1024 thr; 16 waves = 8 n-tiles x 2 ks-halves; each wave
//    owns all 4 m-tiles, ONE un-chained MFMA per (mt,f) on its ks-half.
//    B-frag LDS reads 16 b128/f/CU.
//  - B tiles staged to LDS once per block via global_load_lds, double
//    buffer 2 x 48 KB, issue-early/drain-late, one barrier per phase.
//  - xr on the vmem pipe (L1-resident 10 KB slice), no persistent rotation.
//  - Partial cur summed once per layer via component-sliced rbuf (32 KB,
//    conflict-free). Valid by linearity of the x-scale over the g-sum.
//
// wt layout (prep output), tile tl = l*39+f (layer0 g zero-padded):
//   wt[tl*8192 + ((ks*4 + q)*128 + n)*8 + j] = bf16(W_l[f*64 + ks*32+q*8+j][n])

#define NF      39
#define LCH     128
#define NLAYER  3
#define NFT     (NLAYER * NF)    // 117 f-tiles
#define TILE_SH 8192             // shorts per B tile (16 KB)
#define PH_T    3                // tiles per phase
#define BUF_SH  (PH_T * TILE_SH) // 24576 shorts per buffer (48 KB)
#define SLN     64               // slices per block (4 batches x 16 d)
#define NPH     (NF / PH_T)      // 13 phases per layer
#define XSTR    (NF * 16)        // 624 floats per batch row

typedef __bf16        bf16x8 __attribute__((ext_vector_type(8)));
typedef unsigned int  uint4v __attribute__((ext_vector_type(4)));
typedef float         f32x4  __attribute__((ext_vector_type(4)));

__device__ __forceinline__ unsigned short f2bf_rne(float f) {
    unsigned u = __float_as_uint(f);
    u += 0x7fffu + ((u >> 16) & 1u);
    return (unsigned short)(u >> 16);
}

// ---------------- prep: W fp32 -> bf16 frag-ready tiles in ws ----------------
__global__ void cin_prep(const float* __restrict__ W0,
                         const float* __restrict__ W1,
                         const float* __restrict__ W2,
                         unsigned short* __restrict__ wt)
{
    const int t = blockIdx.x * blockDim.x + threadIdx.x; // ((tl*2+ks)*4+q)*128 + n
    if (t >= NFT * 1024) return;
    const int n  = t & 127;
    const int q  = (t >> 7) & 3;
    const int ks = (t >> 9) & 1;
    const int tl = t >> 10;
    const int l  = tl / NF;
    const int f  = tl - l * NF;
    const float* W = (l == 0) ? W0 : (l == 1) ? W1 : W2;

    unsigned short v[8];
    #pragma unroll
    for (int j = 0; j < 8; ++j) {
        const int g = ks * 32 + q * 8 + j;
        float w = 0.0f;
        if (l == 0) { if (g < NF) w = W[(f * NF + g) * LCH + n]; }
        else        { w = W[(f * 64 + g) * LCH + n]; }
        v[j] = f2bf_rne(w);
    }
    uint4v pv;
    #pragma unroll
    for (int i = 0; i < 4; ++i)
        pv[i] = (unsigned)v[2 * i] | ((unsigned)v[2 * i + 1] << 16);
    ((uint4v*)wt)[t] = pv;   // 16B coalesced
}

// ---------------- main ----------------
__global__ __launch_bounds__(1024, 4) void cin_mfma(
    const float* __restrict__ x,
    const unsigned short* __restrict__ wt,
    const float* __restrict__ b0p,
    const float* __restrict__ b1p,
    const float* __restrict__ b2p,
    float* __restrict__ out)
{
    __shared__ __align__(16) unsigned short Bbuf[2 * BUF_SH];   // 96 KB B dbuf
    __shared__ __align__(16) unsigned short hfrag[8 * SLN * 8]; // 8 KB
    __shared__ __align__(16) float rbuf[16 * 512];              // 32 KB ks exch

    const int tid  = threadIdx.x;
    const int lane = tid & 63;
    const int w    = tid >> 6;      // wave 0..15
    const int wn   = w & 7;         // n-tile
    const int ksh  = w >> 3;        // ks-half
    const int q    = lane >> 4;     // quad 0..3
    const int c    = lane & 15;
    const int nc   = wn * 16 + c;   // this lane's output channel
    const int bb   = blockIdx.x * 4;

    // zero hfrag (covers layer-0 padding g in [39,64)): 8 KB = 512 * 16B
    if (tid < 512) {
        f32x4 z4 = {0.f, 0.f, 0.f, 0.f};
        ((f32x4*)hfrag)[tid] = z4;
    }
    __syncthreads();

    // stage layer-0 h (bf16) from x (contiguous 4*39*16 = 2496 floats)
    for (int i = tid; i < 4 * NF * 16; i += 1024) {
        const float v = x[bb * XSTR + i];
        const int lb = i / XSTR;
        const int r  = i - lb * XSTR;
        const int f  = r >> 4;
        const int d  = r & 15;
        const int sl = lb * 16 + d;
        hfrag[((f >> 3) * SLN + sl) * 8 + (f & 7)] = f2bf_rne(v);
    }

    // issue initial B staging: tiles 0..2 -> buf0 (16 waves x 1 KB per tile)
    {
        const unsigned short* src = wt + w * 512 + lane * 8;
        unsigned short* dst = Bbuf + w * 512;
        #pragma unroll
        for (int k = 0; k < PH_T; ++k)
            __builtin_amdgcn_global_load_lds((const void*)(src + k * TILE_SH),
                                             (void*)(dst + k * TILE_SH), 16, 0, 0);
    }

    // xr global base: x[(bb+mt)*624 + f*16 + q*4 .. +3], 16B aligned
    const float* xb = x + bb * XSTR + q * 4;

    __syncthreads();   // hfrag + buf0 ready

    int cb = 0;
    #pragma unroll 1
    for (int l = 0; l < NLAYER; ++l) {
        // hoist A-frags for OWN ks-half only (named, 16 VGPR)
        bf16x8 a0 = *(const bf16x8*)&hfrag[((ksh * 4 + q) * SLN + 0 * 16 + c) * 8];
        bf16x8 a1 = *(const bf16x8*)&hfrag[((ksh * 4 + q) * SLN + 1 * 16 + c) * 8];
        bf16x8 a2 = *(const bf16x8*)&hfrag[((ksh * 4 + q) * SLN + 2 * 16 + c) * 8];
        bf16x8 a3 = *(const bf16x8*)&hfrag[((ksh * 4 + q) * SLN + 3 * 16 + c) * 8];

        const f32x4 zz = {0.f, 0.f, 0.f, 0.f};
        f32x4 cur0 = zz, cur1 = zz, cur2 = zz, cur3 = zz;

        #pragma unroll 1
        for (int ph = 0; ph < NPH; ++ph) {
            const int tl = l * NF + ph * PH_T;

            // issue next phase's staging first (issue-early / drain-late)
            const int nb = tl + PH_T;
            if (nb < NFT) {
                const unsigned short* src = wt + (size_t)nb * TILE_SH + w * 512 + lane * 8;
                unsigned short* dst = &Bbuf[(cb ^ 1) * BUF_SH + w * 512];
                #pragma unroll
                for (int k = 0; k < PH_T; ++k)
                    __builtin_amdgcn_global_load_lds((const void*)(src + k * TILE_SH),
                                                     (void*)(dst + k * TILE_SH), 16, 0, 0);
            }

            // per-lane B read base for this phase, OWN ks-half only
            const unsigned short* rbq = Bbuf + cb * BUF_SH + ((ksh * 4 + q) * 128 + nc) * 8;

            const int f0 = ph * PH_T;
            // One B-frag live at a time (4 regs, was 12); xr loads split 2+2
            // (<=8 regs live, was 16). Peak ~56 VGPR -> no spill at the
            // empirical 64-VGPR wall.
            #define F_ITER(KT, FI)                                                  \
            {                                                                       \
                const bf16x8 Bk = *(const bf16x8*)(rbq + (KT) * TILE_SH);           \
                const f32x4 xr0 = *(const f32x4*)(xb + 0 * XSTR + (FI) * 16);       \
                const f32x4 xr1 = *(const f32x4*)(xb + 1 * XSTR + (FI) * 16);       \
                f32x4 sv;                                                           \
                sv = __builtin_amdgcn_mfma_f32_16x16x32_bf16(a0, Bk, zz, 0, 0, 0);  \
                _Pragma("unroll")                                                   \
                for (int r = 0; r < 4; ++r) cur0[r] = fmaf(xr0[r], sv[r], cur0[r]); \
                sv = __builtin_amdgcn_mfma_f32_16x16x32_bf16(a1, Bk, zz, 0, 0, 0);  \
                _Pragma("unroll")                                                   \
                for (int r = 0; r < 4; ++r) cur1[r] = fmaf(xr1[r], sv[r], cur1[r]); \
                const f32x4 xr2 = *(const f32x4*)(xb + 2 * XSTR + (FI) * 16);       \
                const f32x4 xr3 = *(const f32x4*)(xb + 3 * XSTR + (FI) * 16);       \
                sv = __builtin_amdgcn_mfma_f32_16x16x32_bf16(a2, Bk, zz, 0, 0, 0);  \
                _Pragma("unroll")                                                   \
                for (int r = 0; r < 4; ++r) cur2[r] = fmaf(xr2[r], sv[r], cur2[r]); \
                sv = __builtin_amdgcn_mfma_f32_16x16x32_bf16(a3, Bk, zz, 0, 0, 0);  \
                _Pragma("unroll")                                                   \
                for (int r = 0; r < 4; ++r) cur3[r] = fmaf(xr3[r], sv[r], cur3[r]); \
            }
            F_ITER(0, f0 + 0)
            F_ITER(1, f0 + 1)
            F_ITER(2, f0 + 2)
            #undef F_ITER

            __syncthreads();   // drain staging + buffer handoff
            cb ^= 1;
        }

        // ---------------- layer end: ks-half reduce + epilogue ----------------
        if (ksh == 1) {
            // component-sliced: consecutive lanes -> consecutive dwords (no conflicts)
            #define RW(MT, CURV)                                                    \
            _Pragma("unroll")                                                       \
            for (int r = 0; r < 4; ++r)                                             \
                rbuf[((MT) * 4 + r) * 512 + wn * 64 + lane] = CURV[r];
            RW(0, cur0) RW(1, cur1) RW(2, cur2) RW(3, cur3)
            #undef RW
        }
        __syncthreads();
        if (ksh == 0) {
            const float* bp = (l == 0) ? b0p : (l == 1) ? b1p : b2p;
            const float bias = bp[nc];
            float v0[4], v1[4], v2[4], v3[4];
            #define RD(MT, CURV, VV)                                                \
            _Pragma("unroll")                                                       \
            for (int r = 0; r < 4; ++r)                                             \
                VV[r] = fmaxf(CURV[r] +                                             \
                              rbuf[((MT) * 4 + r) * 512 + wn * 64 + lane] +         \
                              bias, 0.f);
            RD(0, cur0, v0) RD(1, cur1, v1) RD(2, cur2, v2) RD(3, cur3, v3)
            #undef RD

            if (l < 2 && wn < 4) {
                // h channels (nc < 64): write next layer's h (C row = q*4+r)
                #define HWR(MT, VV)                                                 \
                _Pragma("unroll")                                                   \
                for (int r = 0; r < 4; ++r)                                         \
                    hfrag[((nc >> 3) * SLN + (MT) * 16 + q * 4 + r) * 8 + (nc & 7)] \
                        = f2bf_rne(VV[r]);
                HWR(0, v0) HWR(1, v1) HWR(2, v2) HWR(3, v3)
                #undef HWR
            } else {
                // direct channels: reduce over d (= q*4+r) and store
                // l==0: nc 64..127 -> out 0..63 ; l==1: nc 64..127 -> out 64..127 ;
                // l==2: nc 0..127 -> out 128..255
                const int outcol = (l == 0) ? nc - 64 : (l == 1) ? nc : 128 + nc;
                #define DST(MT, VV)                                                 \
                {                                                                   \
                    float sacc = VV[0] + VV[1] + VV[2] + VV[3];                     \
                    sacc += __shfl_xor(sacc, 16, 64);                               \
                    sacc += __shfl_xor(sacc, 32, 64);                               \
                    if (lane < 16) out[(bb + (MT)) * 256 + outcol] = sacc;          \
                }
                DST(0, v0) DST(1, v1) DST(2, v2) DST(3, v3)
                #undef DST
            }
        }
        if (l < 2) __syncthreads();   // h writes visible before next A-hoist
    }
}

extern "C" void kernel_launch(void* const* d_in, const int* in_sizes, int n_in,
                              void* d_out, int out_size, void* d_ws, size_t ws_size,
                              hipStream_t stream) {
    const float* x  = (const float*)d_in[0];
    const float* W0 = (const float*)d_in[1];
    const float* W1 = (const float*)d_in[2];
    const float* W2 = (const float*)d_in[3];
    const float* b0 = (const float*)d_in[4];
    const float* b1 = (const float*)d_in[5];
    const float* b2 = (const float*)d_in[6];
    float* out = (float*)d_out;
    unsigned short* wt = (unsigned short*)d_ws;  // 117*8192*2 B = 1.87 MB

    const int prep_threads = NFT * 1024;         // 119808
    cin_prep<<<(prep_threads + 255) / 256, 256, 0, stream>>>(W0, W1, W2, wt);
    cin_mfma<<<256, 1024, 0, stream>>>(x, wt, b0, b1, b2, out);
}

// Round 9
// 116.709 us; speedup vs baseline: 1.3639x; 1.3639x over previous
//
#include <hip/hip_runtime.h>

// CIN fused 3-layer, bf16 MFMA (R15): swapped-operand ks-split, LDS-only loop.
// cur[sl,n] = sum_f x_f[sl] * S_f[sl,n],  S_f = sum_g h_g[sl] * W[f*64+g, n].
//
// Register law (R9-R14, 6 data points): this toolchain gives these kernels
// exactly 64 VGPR; only demand <= ~60 runs clean (R8: 52). Global loads in
// the K-loop get hoisted per-phase (+40 regs) -> spill. Rule: K-loop loads
// must be LDS-only, and the algorithm must need few persistent regs.
//
// R15 structure (all pieces individually verified in passing rounds):
//  - swapped mfma(A=W^T, B=h) [R9's math, passed]: h is B-operand ->
//    4 persistent hb frags (16 regs, own ks-half); W streams LDS->VGPR
//    1 b128/f/wave, shared by all 4 st MFMAs.
//  - C-layout: row=n (q*4+r), col=sl (st*16+c) -> x_f[sl] per-lane f32x4
//    over st via xS[d][f][st] (slot stride 41: 2-way banks = free);
//    1 b128/f/wave, 4-reg transient. Zero global loads in the loop.
//  - ks-split waves (8n x 2ks) [R13, passed]; partial cur exchanged once
//    per layer through the DEAD Bbuf half (no extra LDS).
//  - DMA dbuf staging, PH_T=4 (64 KB/buf), 1 barrier/phase [R8 frame].
//  Peak regs ~52 = R8's proven point. LDS/f/CU: 16+16 b128 + DMA ~ 512 cy.
//
// wt layout (R9 prep, verified), tile tl = l*40+f (f=39 zero tile):
//   wt[tl*8192 + ((ks*128 + n)*4 + q)*8 + j] = bf16(W_l[f*64 + ks*32+q*8+j][n])
// lane (q,c) of wave (wn,ksh) reads A-frag at ksh*4096 + (wn*16+c)*32 + q*8.

#define NF      39
#define LCH     128
#define NLAYER  3
#define LSTR    40                  // padded tiles per layer
#define NTILES  (NLAYER * LSTR)     // 120
#define TILE_SH 8192                // shorts per tile (16 KB)
#define PH_T    4                   // tiles per phase
#define BUF_SH  (PH_T * TILE_SH)    // 32768 shorts (64 KB)
#define NPH     (LSTR / PH_T)       // 10 phases per layer
#define SLN     64                  // slices per block (4 batches x 16 d)
#define XSL     41                  // xS f-slot stride (bank spread, 2-way)
#define XSTR    (NF * 16)           // 624 floats per batch row

typedef __bf16        bf16x8 __attribute__((ext_vector_type(8)));
typedef unsigned int  uint4v __attribute__((ext_vector_type(4)));
typedef float         f32x4  __attribute__((ext_vector_type(4)));

__device__ __forceinline__ unsigned short f2bf_rne(float f) {
    unsigned u = __float_as_uint(f);
    u += 0x7fffu + ((u >> 16) & 1u);
    return (unsigned short)(u >> 16);
}

// ---------------- prep: W fp32 -> bf16 frag-ready transposed tiles (R9) ----
__global__ void cin_prep(const float* __restrict__ W0,
                         const float* __restrict__ W1,
                         const float* __restrict__ W2,
                         unsigned short* __restrict__ wt)
{
    const int t = blockIdx.x * blockDim.x + threadIdx.x; // tl*1024 + ks*512 + n*4 + q
    if (t >= NTILES * 1024) return;
    const int q  = t & 3;
    const int n  = (t >> 2) & 127;
    const int ks = (t >> 9) & 1;
    const int tl = t >> 10;
    const int l  = tl / LSTR;
    const int f  = tl - l * LSTR;
    const float* W = (l == 0) ? W0 : (l == 1) ? W1 : W2;

    unsigned short v[8];
    #pragma unroll
    for (int j = 0; j < 8; ++j) {
        const int g = ks * 32 + q * 8 + j;
        float w = 0.0f;
        if (f < NF) {
            if (l == 0) { if (g < NF) w = W[(f * NF + g) * LCH + n]; }
            else        { w = W[(f * 64 + g) * LCH + n]; }
        }
        v[j] = f2bf_rne(w);
    }
    uint4v pv;
    #pragma unroll
    for (int i = 0; i < 4; ++i)
        pv[i] = (unsigned)v[2 * i] | ((unsigned)v[2 * i + 1] << 16);
    ((uint4v*)wt)[t] = pv;   // 16B coalesced
}

// ---------------- main ----------------
__global__ __launch_bounds__(1024, 4) void cin_mfma(
    const float* __restrict__ x,
    const unsigned short* __restrict__ wt,
    const float* __restrict__ b0p,
    const float* __restrict__ b1p,
    const float* __restrict__ b2p,
    float* __restrict__ out)
{
    __shared__ __align__(16) unsigned short Bbuf[2 * BUF_SH];   // 128 KB W dbuf
    __shared__ __align__(16) unsigned short hfrag[8 * SLN * 8]; // 8 KB
    __shared__ __align__(16) float xS[16 * XSL * 4];            // 10.25 KB [d][f][st]
    __shared__ float biasl[NLAYER * LCH];                       // 1.5 KB

    const int tid  = threadIdx.x;
    const int lane = tid & 63;
    const int w    = tid >> 6;      // wave 0..15
    const int wn   = w & 7;         // n-tile
    const int ksh  = w >> 3;        // ks-half (g in [ksh*32, ksh*32+32))
    const int q    = lane >> 4;     // quad 0..3
    const int c    = lane & 15;
    const int bb   = blockIdx.x * 4;

    // zero hfrag first (covers layer-0 padding g in [39,64))
    if (tid < 512) {
        f32x4 z4 = {0.f, 0.f, 0.f, 0.f};
        ((f32x4*)hfrag)[tid] = z4;
    }
    __syncthreads();   // zero visible before partial hfrag writes

    // stage x: hfrag (layer-0 h, bf16) + xS[d][f][st] (fp32)
    for (int i = tid; i < 4 * XSTR; i += 1024) {
        const float v = x[bb * XSTR + i];
        const int lb = i / XSTR;
        const int r  = i - lb * XSTR;
        const int f  = r >> 4;
        const int d  = r & 15;
        hfrag[((f >> 3) * SLN + lb * 16 + d) * 8 + (f & 7)] = f2bf_rne(v);
        xS[(d * XSL + f) * 4 + lb] = v;
    }
    // zero xS f=39 slot (read at f=39; W tile is zero but NaN*0 would poison)
    if (tid < 64) xS[((tid >> 2) * XSL + NF) * 4 + (tid & 3)] = 0.f;
    if (tid < NLAYER * LCH)
        biasl[tid] = (tid < 128) ? b0p[tid] : (tid < 256) ? b1p[tid-128] : b2p[tid-256];

    // prologue B staging: tiles 0..3 -> buf0 (each wave 1 KB per tile)
    {
        const unsigned short* src = wt + w * 512 + lane * 8;
        unsigned short* dst = Bbuf + w * 512;
        #pragma unroll
        for (int k = 0; k < PH_T; ++k)
            __builtin_amdgcn_global_load_lds((const void*)(src + k * TILE_SH),
                                             (void*)(dst + k * TILE_SH), 16, 0, 0);
    }
    __syncthreads();   // hfrag, xS, bias, buf0 ready

    // per-lane constants (32-bit LDS offsets only)
    const int bofs = ksh * 4096 + wn * 512 + c * 32 + q * 8;  // shorts within tile
    const int xbl  = c * XSL;                                  // xS slot base

    int cb = 0;
    #pragma unroll 1
    for (int l = 0; l < NLAYER; ++l) {
        // hoist h B-frags (own ks-half, 4 st): 16 VGPR persistent
        bf16x8 hb0 = *(const bf16x8*)&hfrag[((ksh * 4 + q) * SLN +  0 + c) * 8];
        bf16x8 hb1 = *(const bf16x8*)&hfrag[((ksh * 4 + q) * SLN + 16 + c) * 8];
        bf16x8 hb2 = *(const bf16x8*)&hfrag[((ksh * 4 + q) * SLN + 32 + c) * 8];
        bf16x8 hb3 = *(const bf16x8*)&hfrag[((ksh * 4 + q) * SLN + 48 + c) * 8];

        const f32x4 zz = {0.f, 0.f, 0.f, 0.f};
        f32x4 cur0 = zz, cur1 = zz, cur2 = zz, cur3 = zz;

        #pragma unroll 1
        for (int p = 0; p < NPH; ++p) {
            // stage next phase (issue-early / drain at the phase barrier)
            const int nbt = l * LSTR + p * PH_T + PH_T;
            if (nbt < NTILES) {
                const unsigned short* src = wt + (size_t)nbt * TILE_SH + w * 512 + lane * 8;
                unsigned short* dst = &Bbuf[(cb ^ 1) * BUF_SH + w * 512];
                #pragma unroll
                for (int k = 0; k < PH_T; ++k)
                    __builtin_amdgcn_global_load_lds((const void*)(src + k * TILE_SH),
                                                     (void*)(dst + k * TILE_SH), 16, 0, 0);
            }
            const unsigned short* tb = Bbuf + cb * BUF_SH + bofs;
            const int p4 = p * PH_T;

            // per f: 1 wa b128 (shared by 4 MFMAs) + 1 xr b128; all LDS.
            #define F_ITER(K)                                                       \
            {                                                                       \
                const f32x4 xr = *(const f32x4*)&xS[(xbl + p4 + (K)) * 4];          \
                const bf16x8 wa = *(const bf16x8*)(tb + (K) * TILE_SH);             \
                f32x4 sv;                                                           \
                sv = __builtin_amdgcn_mfma_f32_16x16x32_bf16(wa, hb0, zz, 0, 0, 0); \
                _Pragma("unroll")                                                   \
                for (int r = 0; r < 4; ++r) cur0[r] = fmaf(xr[0], sv[r], cur0[r]);  \
                sv = __builtin_amdgcn_mfma_f32_16x16x32_bf16(wa, hb1, zz, 0, 0, 0); \
                _Pragma("unroll")                                                   \
                for (int r = 0; r < 4; ++r) cur1[r] = fmaf(xr[1], sv[r], cur1[r]);  \
                sv = __builtin_amdgcn_mfma_f32_16x16x32_bf16(wa, hb2, zz, 0, 0, 0); \
                _Pragma("unroll")                                                   \
                for (int r = 0; r < 4; ++r) cur2[r] = fmaf(xr[2], sv[r], cur2[r]);  \
                sv = __builtin_amdgcn_mfma_f32_16x16x32_bf16(wa, hb3, zz, 0, 0, 0); \
                _Pragma("unroll")                                                   \
                for (int r = 0; r < 4; ++r) cur3[r] = fmaf(xr[3], sv[r], cur3[r]);  \
            }
            F_ITER(0) F_ITER(1) F_ITER(2) F_ITER(3)
            #undef F_ITER

            __syncthreads();   // drain staging + buffer handoff
            cb ^= 1;
        }

        // ------- layer end: ks-reduce through the DEAD Bbuf half -------
        // after the last flip, Bbuf[cb^1] is the just-consumed buffer (dead);
        // Bbuf[cb] holds next layer's phase-0 tiles (staged during p=9).
        float* exch = (float*)(Bbuf + (cb ^ 1) * BUF_SH);   // 32 KB of 64 used
        if (ksh == 1) {
            // component-sliced: consecutive lanes -> consecutive dwords
            #define RW(ST, CURV)                                                    \
            _Pragma("unroll")                                                       \
            for (int r = 0; r < 4; ++r)                                             \
                exch[((ST) * 4 + r) * 512 + wn * 64 + lane] = CURV[r];
            RW(0, cur0) RW(1, cur1) RW(2, cur2) RW(3, cur3)
            #undef RW
        }
        __syncthreads();
        if (ksh == 0) {
            const f32x4 bq = *(const f32x4*)&biasl[l * LCH + wn * 16 + q * 4];
            float v0[4], v1[4], v2[4], v3[4];
            #define RD(ST, CURV, VV)                                                \
            _Pragma("unroll")                                                       \
            for (int r = 0; r < 4; ++r)                                             \
                VV[r] = fmaxf(CURV[r] +                                             \
                              exch[((ST) * 4 + r) * 512 + wn * 64 + lane] +         \
                              bq[r], 0.f);
            RD(0, cur0, v0) RD(1, cur1, v1) RD(2, cur2, v2) RD(3, cur3, v3)
            #undef RD

            if (l < 2 && wn < 4) {
                // h channels (n<64): write next layer's h; n = wn*16+q*4+r,
                // sl = st*16+c
                #define HWR(ST, VV)                                                 \
                _Pragma("unroll")                                                   \
                for (int r = 0; r < 4; ++r) {                                       \
                    const int n = wn * 16 + q * 4 + r;                              \
                    hfrag[((n >> 3) * SLN + (ST) * 16 + c) * 8 + (n & 7)] =         \
                        f2bf_rne(VV[r]);                                            \
                }
                HWR(0, v0) HWR(1, v1) HWR(2, v2) HWR(3, v3)
                #undef HWR
            } else {
                // direct: reduce over d (= c lanes) and store
                // l==0: n 64..127 -> out 0..63; l==1: n -> 64..127; l==2: 128+n
                #define DST(ST, VV)                                                 \
                _Pragma("unroll")                                                   \
                for (int r = 0; r < 4; ++r) {                                       \
                    float s = VV[r];                                                \
                    s += __shfl_xor(s, 1, 64);                                      \
                    s += __shfl_xor(s, 2, 64);                                      \
                    s += __shfl_xor(s, 4, 64);                                      \
                    s += __shfl_xor(s, 8, 64);                                      \
                    if (c == 0) {                                                   \
                        const int n = wn * 16 + q * 4 + r;                          \
                        const int outcol = (l == 0) ? n - 64                        \
                                         : (l == 1) ? n : 128 + n;                  \
                        out[(bb + (ST)) * 256 + outcol] = s;                        \
                    }                                                               \
                }
                DST(0, v0) DST(1, v1) DST(2, v2) DST(3, v3)
                #undef DST
            }
        }
        if (l < 2) __syncthreads();   // h writes visible before next hb hoist
    }
}

extern "C" void kernel_launch(void* const* d_in, const int* in_sizes, int n_in,
                              void* d_out, int out_size, void* d_ws, size_t ws_size,
                              hipStream_t stream) {
    const float* x  = (const float*)d_in[0];
    const float* W0 = (const float*)d_in[1];
    const float* W1 = (const float*)d_in[2];
    const float* W2 = (const float*)d_in[3];
    const float* b0 = (const float*)d_in[4];
    const float* b1 = (const float*)d_in[5];
    const float* b2 = (const float*)d_in[6];
    float* out = (float*)d_out;
    unsigned short* wt = (unsigned short*)d_ws;  // 120*8192*2 B = 1.97 MB

    const int prep_threads = NTILES * 1024;      // 122880
    cin_prep<<<(prep_threads + 255) / 256, 256, 0, stream>>>(W0, W1, W2, wt);
    cin_mfma<<<256, 1024, 0, stream>>>(x, wt, b0, b1, b2, out);
}